// Round 1
// 122.912 us; speedup vs baseline: 1.0147x; 1.0147x over previous
//
#include <hip/hip_runtime.h>
#include <cstddef>

// CGCoupler: out[n, ro[k]] += cg[k] * x1[n, r1[k]] * x2[n, r2[k]]
// Fixed structure: METADATA=[64,64,32,32], lmax=3, rep_dim=out_dim=640.
// Irrep layout (inputs and output): l0 @ [0,64) W=64; l1 @ [64,256) W=64;
// l2 @ [256,416) W=32; l3 @ [416,640) W=32.
//
// R6: R5's verified compile-time-CG compute mapping (one wave = 2 rows,
// lane -> (sub, t) channel ownership) is unchanged. Data movement is
// rebuilt around an LDS bounce so ALL global traffic is dwordx4:
//   stage: 8 rows x 640 f32 x 2 inputs (40 KB) loaded as float4
//          (1 KB/wave/instr, perfectly coalesced)
//   compute: per-channel ds_read_b32 (2-way bank alias only = free)
//   store: scatter acc into lds1 (each thread writes exactly the
//          addresses it read -> no extra barrier), then float4
//          nontemporal stores.
// Rationale: R5's scalar 4B/lane global streams hit ~50% of the float4
// copy ceiling (kernel ~40us vs ~20us traffic floor of 125.8 MB).

#define BLOCK 256
#define RPB 8   // rows per block = 2 rows/wave * 4 waves

typedef float f32x4 __attribute__((ext_vector_type(4)));

// ---------------- compile-time CG machinery (verified in R4/R5) ----------------

constexpr double cfact(int n) { double r = 1; for (int i = 2; i <= n; ++i) r *= i; return r; }

constexpr double csqrt_(double x) {
    if (x <= 0) return 0;
    double g = x;
    for (int i = 0; i < 80; ++i) g = 0.5 * (g + x / g);
    return g;
}

constexpr double cg_complex(int j1, int m1, int j2, int m2, int j, int m) {
    if (m1 + m2 != m) return 0;
    int dj = (j1 - j2 < 0) ? (j2 - j1) : (j1 - j2);
    if (j < dj || j > j1 + j2) return 0;
    double pre = csqrt_((2 * j + 1) * cfact(j1 + j2 - j) * cfact(j1 - j2 + j)
                        * cfact(-j1 + j2 + j) / cfact(j1 + j2 + j + 1));
    pre *= csqrt_(cfact(j1 + m1) * cfact(j1 - m1) * cfact(j2 + m2)
                  * cfact(j2 - m2) * cfact(j + m) * cfact(j - m));
    int kmin = 0;
    if (j2 - j - m1 > kmin) kmin = j2 - j - m1;
    if (j1 + m2 - j > kmin) kmin = j1 + m2 - j;
    int kmax = j1 + j2 - j;
    if (j1 - m1 < kmax) kmax = j1 - m1;
    if (j2 + m2 < kmax) kmax = j2 + m2;
    double s = 0;
    for (int k = kmin; k <= kmax; ++k) {
        double t = 1.0 / (cfact(k) * cfact(j1 + j2 - j - k) * cfact(j1 - m1 - k)
                          * cfact(j2 + m2 - k) * cfact(j - j2 + m1 + k) * cfact(j - j1 - m2 + k));
        s += (k & 1) ? -t : t;
    }
    return pre * s;
}

struct CD { double re, im; };
constexpr CD cmul(CD a, CD b) { return {a.re * b.re - a.im * b.im, a.re * b.im + a.im * b.re}; }

// A[a][col] of _csh_to_rsh(l): rows a = l+m' (complex m'), cols = l+m (real m)
constexpr CD A_ent(int l, int a, int col) {
    const double s2 = 0.70710678118654752440;
    int m = col - l, mp = a - l;
    if (m < 0) {
        double sgn = ((-m) & 1) ? -1.0 : 1.0;   // (-1)^m
        if (mp == m)  return {0.0, s2};          //  1j*s2
        if (mp == -m) return {0.0, -sgn * s2};   // -1j*(-1)^m*s2
        return {0.0, 0.0};
    } else if (m == 0) {
        return (mp == 0) ? CD{1.0, 0.0} : CD{0.0, 0.0};
    } else {
        double sgn = (m & 1) ? -1.0 : 1.0;
        if (mp == m)  return {sgn * s2, 0.0};
        if (mp == -m) return {s2, 0.0};
        return {0.0, 0.0};
    }
}

// rsh = Re( einsum('abc,ai,bj,ck', csh, A(j1), A(j2), conj(A(j))) * (-1j)^(j1+j2+j) )
constexpr double rsh_cg(int j1, int j2, int j, int i, int jj, int k) {
    double re = 0, im = 0;
    for (int m1 = -j1; m1 <= j1; ++m1)
        for (int m2 = -j2; m2 <= j2; ++m2) {
            int m = m1 + m2;
            if (m < -j || m > j) continue;
            double c = cg_complex(j1, m1, j2, m2, j, m);
            if (c == 0) continue;
            CD a1 = A_ent(j1, j1 + m1, i);
            CD a2 = A_ent(j2, j2 + m2, jj);
            CD a3 = A_ent(j, j + m, k);
            a3.im = -a3.im;                      // conj
            CD p = cmul(cmul(a1, a2), a3);
            re += c * p.re;
            im += c * p.im;
        }
    int ph = (j1 + j2 + j) & 3;                  // multiply by (-i)^ph, take Re
    if (ph == 0) return re;
    if (ph == 1) return im;
    if (ph == 2) return -re;
    return -im;
}

// ---------------- compile-time-unrolled term emission ----------------

template <int L1, int L2, int LO, int IDX, int NT>
__device__ __forceinline__ void terms_rec(const float* __restrict__ x1v,
                                          const float* __restrict__ x2v,
                                          float* __restrict__ acc) {
    if constexpr (IDX < NT) {
        constexpr int N2 = 2 * L2 + 1, NO = 2 * LO + 1;
        constexpr int u1 = IDX / (N2 * NO);
        constexpr int u2 = (IDX / NO) % N2;
        constexpr int uo = IDX % NO;
        constexpr double v = rsh_cg(L1, L2, LO, u1, u2, uo);
        constexpr float cgv = (v > 1e-12 || v < -1e-12) ? (float)v : 0.0f;
        constexpr int SB1 = (L1 == 0) ? 0 : (L1 == 1) ? 1 : (L1 == 2) ? 4 : 9;
        constexpr int SB2 = (L2 == 0) ? 0 : (L2 == 1) ? 1 : (L2 == 2) ? 4 : 9;
        constexpr int SBO = (LO == 0) ? 0 : (LO == 1) ? 1 : (LO == 2) ? 4 : 9;
        if constexpr (cgv != 0.0f) {
            acc[SBO + uo] += cgv * x1v[SB1 + u1] * x2v[SB2 + u2];
        }
        terms_rec<L1, L2, LO, IDX + 1, NT>(x1v, x2v, acc);
    }
}

template <int L1, int L2, int LO>
__device__ __forceinline__ void proc_block(const float* __restrict__ x1v,
                                           const float* __restrict__ x2v,
                                           float* __restrict__ acc) {
    terms_rec<L1, L2, LO, 0, (2 * L1 + 1) * (2 * L2 + 1) * (2 * LO + 1)>(x1v, x2v, acc);
}

// ---------------- main kernel ----------------

__global__ __launch_bounds__(BLOCK) void cg_main_kernel(
    const float* __restrict__ x1, const float* __restrict__ x2,
    float* __restrict__ out, int N)
{
    __shared__ f32x4 lds1v[RPB * 160];   // 20 KB: x1 rows, reused for output
    __shared__ f32x4 lds2v[RPB * 160];   // 20 KB: x2 rows
    float* lds1 = (float*)lds1v;
    float* lds2 = (float*)lds2v;

    const int tid = threadIdx.x;
    const int r0  = blockIdx.x * RPB;
    const int nrows = (N - r0 < RPB) ? (N - r0) : RPB;
    const int nq = nrows * 160;                      // float4s to move
    const size_t base = (size_t)r0 * 640;

    // ---- stage: dwordx4 global -> LDS (1 KB per wave per instruction) ----
    const f32x4* __restrict__ s1 = (const f32x4*)(x1 + base);
    const f32x4* __restrict__ s2 = (const f32x4*)(x2 + base);
#pragma unroll
    for (int i = 0; i < 5; ++i) {
        const int idx = i * BLOCK + tid;
        if (idx < nq) {
            lds1v[idx] = s1[idx];
            lds2v[idx] = s2[idx];
        }
    }
    __syncthreads();

    // ---- compute: identical per-channel mapping to verified R5 ----
    const int lr = tid >> 5;       // local row 0..7 (wave w holds rows 2w, 2w+1)
    const int t  = tid & 31;       // channel within 32-wide segment

    if (lr < nrows) {
        const float* p1 = lds1 + lr * 640;
        const float* p2 = lds2 + lr * 640;

        // bank T: channel t      (slots 0..15, all l)
        // bank U: channel t+32   (slots 0..3, l0/l1 only)
        float x1t[16], x2t[16], acct[16];
        float x1u[4],  x2u[4],  accu[4];
#pragma unroll
        for (int i = 0; i < 16; ++i) acct[i] = 0.f;
#pragma unroll
        for (int i = 0; i < 4; ++i) accu[i] = 0.f;

        x1t[0] = p1[t];       x2t[0] = p2[t];
        x1u[0] = p1[t + 32];  x2u[0] = p2[t + 32];
#pragma unroll
        for (int u = 0; u < 3; ++u) {
            x1t[1 + u] = p1[64 + u * 64 + t];
            x2t[1 + u] = p2[64 + u * 64 + t];
            x1u[1 + u] = p1[64 + u * 64 + t + 32];
            x2u[1 + u] = p2[64 + u * 64 + t + 32];
        }
#pragma unroll
        for (int u = 0; u < 5; ++u) {
            x1t[4 + u] = p1[256 + u * 32 + t];
            x2t[4 + u] = p2[256 + u * 32 + t];
        }
#pragma unroll
        for (int u = 0; u < 7; ++u) {
            x1t[9 + u] = p1[416 + u * 32 + t];
            x2t[9 + u] = p2[416 + u * 32 + t];
        }

        // deg-64 blocks: both channel banks (11 terms each)
        proc_block<0, 0, 0>(x1t, x2t, acct);
        proc_block<0, 1, 1>(x1t, x2t, acct);
        proc_block<1, 0, 1>(x1t, x2t, acct);
        proc_block<0, 0, 0>(x1u, x2u, accu);
        proc_block<0, 1, 1>(x1u, x2u, accu);
        proc_block<1, 0, 1>(x1u, x2u, accu);

        // deg-32 blocks: bank T only, ALL 64 lanes active
        proc_block<1, 1, 0>(x1t, x2t, acct);
        proc_block<1, 1, 1>(x1t, x2t, acct);
        proc_block<1, 2, 1>(x1t, x2t, acct);
        proc_block<2, 1, 1>(x1t, x2t, acct);
        proc_block<0, 2, 2>(x1t, x2t, acct);
        proc_block<2, 0, 2>(x1t, x2t, acct);
        proc_block<1, 1, 2>(x1t, x2t, acct);
        proc_block<1, 2, 2>(x1t, x2t, acct);
        proc_block<2, 1, 2>(x1t, x2t, acct);
        proc_block<0, 3, 3>(x1t, x2t, acct);
        proc_block<3, 0, 3>(x1t, x2t, acct);
        proc_block<1, 2, 3>(x1t, x2t, acct);
        proc_block<2, 1, 3>(x1t, x2t, acct);

        // scatter into lds1 (each thread writes exactly the addresses it
        // read from lds1 -> no cross-thread hazard, no barrier needed here)
        float* po = lds1 + lr * 640;
        po[t]      = acct[0];
        po[t + 32] = accu[0];
#pragma unroll
        for (int u = 0; u < 3; ++u) {
            po[64 + u * 64 + t]      = acct[1 + u];
            po[64 + u * 64 + t + 32] = accu[1 + u];
        }
#pragma unroll
        for (int u = 0; u < 5; ++u)
            po[256 + u * 32 + t] = acct[4 + u];
#pragma unroll
        for (int u = 0; u < 7; ++u)
            po[416 + u * 32 + t] = acct[9 + u];
    }
    __syncthreads();

    // ---- store: dwordx4 nontemporal (output not re-read by us) ----
    f32x4* __restrict__ o4 = (f32x4*)(out + base);
#pragma unroll
    for (int i = 0; i < 5; ++i) {
        const int idx = i * BLOCK + tid;
        if (idx < nq) {
            f32x4 v = lds1v[idx];
            __builtin_nontemporal_store(v, o4 + idx);
        }
    }
}

extern "C" void kernel_launch(void* const* d_in, const int* in_sizes, int n_in,
                              void* d_out, int out_size, void* d_ws, size_t ws_size,
                              hipStream_t stream) {
    // setup_inputs order: x1, x2, cg_tilde, repids_in1, repids_in2, repids_out, out_dim
    const float* x1 = (const float*)d_in[0];
    const float* x2 = (const float*)d_in[1];
    float* out = (float*)d_out;

    const int N = in_sizes[0] / 640;
    const int blocks = (N + RPB - 1) / RPB;
    cg_main_kernel<<<blocks, BLOCK, 0, stream>>>(x1, x2, out, N);
}